// Round 1
// baseline (2823.210 us; speedup 1.0000x reference)
//
#include <hip/hip_runtime.h>
#include <math.h>

#define BN_EPS 1e-5f

__device__ __forceinline__ float gelu_exact(float x) {
    return 0.5f * x * (1.0f + erff(x * 0.70710678118654752f));
}

// ================= encoder conv: k3 s2 p1, NCHW, w(CO,CI,3,3) =================
template<int CI, int CO, int HI, int WI>
__global__ __launch_bounds__(256) void enc_conv(const float* __restrict__ x,
                                                const float* __restrict__ w,
                                                const float* __restrict__ bias,
                                                float* __restrict__ y)
{
    constexpr int HO = HI / 2, WO = WI / 2;
    constexpr int TW = WO / 16;
    const int tid = threadIdx.x;
    const int th = blockIdx.x / TW, tw = blockIdx.x % TW;
    const int cob = blockIdx.y;
    const int n = blockIdx.z;
    const int sg = tid >> 2, cg = tid & 3;
    const int sy = sg >> 3, sx = sg & 7;
    const int OH0 = th * 16, OW0 = tw * 16;
    const int IH0 = OH0 * 2 - 1, IW0 = OW0 * 2 - 1;

    __shared__ __align__(16) float xs[33 * 33];
    __shared__ __align__(16) float wsm[9][16];

    float acc[2][2][4];
    #pragma unroll
    for (int c = 0; c < 4; c++) {
        int co = cob * 16 + cg * 4 + c;
        float bv = (co < CO) ? bias[co] : 0.f;
        acc[0][0][c] = bv; acc[0][1][c] = bv; acc[1][0][c] = bv; acc[1][1][c] = bv;
    }

    for (int ci = 0; ci < CI; ci++) {
        __syncthreads();
        const float* xp = x + ((size_t)(n * CI + ci)) * (HI * WI);
        for (int i = tid; i < 33 * 33; i += 256) {
            int r = i / 33, cc = i - r * 33;
            int ih = IH0 + r, iw = IW0 + cc;
            float v = 0.f;
            if (ih >= 0 && ih < HI && iw >= 0 && iw < WI) v = xp[ih * WI + iw];
            xs[i] = v;
        }
        if (tid < 144) {
            int k = tid >> 4, cl = tid & 15;
            int co = cob * 16 + cl;
            wsm[k][cl] = (co < CO) ? w[((size_t)co * CI + ci) * 9 + k] : 0.f;
        }
        __syncthreads();
        #pragma unroll
        for (int kh = 0; kh < 3; kh++) {
            #pragma unroll
            for (int kw = 0; kw < 3; kw++) {
                float4 wv = *(const float4*)&wsm[kh * 3 + kw][cg * 4];
                #pragma unroll
                for (int dy = 0; dy < 2; dy++) {
                    #pragma unroll
                    for (int dx = 0; dx < 2; dx++) {
                        float xv = xs[(4 * sy + 2 * dy + kh) * 33 + 4 * sx + 2 * dx + kw];
                        acc[dy][dx][0] += xv * wv.x;
                        acc[dy][dx][1] += xv * wv.y;
                        acc[dy][dx][2] += xv * wv.z;
                        acc[dy][dx][3] += xv * wv.w;
                    }
                }
            }
        }
    }
    #pragma unroll
    for (int dy = 0; dy < 2; dy++)
    #pragma unroll
    for (int dx = 0; dx < 2; dx++)
    #pragma unroll
    for (int c = 0; c < 4; c++) {
        int co = cob * 16 + cg * 4 + c;
        if (co < CO)
            y[(((size_t)n * CO + co) * HO + OH0 + 2 * sy + dy) * WO + OW0 + 2 * sx + dx] = acc[dy][dx][c];
    }
}

// ====== decoder convT: k3 s2 p1 outpad1, gather form, w(CI,CO,3,3) ======
template<int CI, int CO, int HI, int WI>
__global__ __launch_bounds__(256) void dec_conv(const float* __restrict__ x,
                                                const float* __restrict__ w,
                                                const float* __restrict__ bias,
                                                float* __restrict__ y)
{
    constexpr int HO = HI * 2, WO = WI * 2;
    constexpr int TW = WO / 16;
    const int tid = threadIdx.x;
    const int th = blockIdx.x / TW, tw = blockIdx.x % TW;
    const int cob = blockIdx.y;
    const int n = blockIdx.z;
    const int sg = tid >> 2, cg = tid & 3;
    const int sy = sg >> 3, sx = sg & 7;
    const int OH0 = th * 16, OW0 = tw * 16;
    const int i0 = OH0 / 2, j0 = OW0 / 2;

    __shared__ __align__(16) float xs[81];
    __shared__ __align__(16) float wsm[9][16];

    float acc[2][2][4];
    #pragma unroll
    for (int c = 0; c < 4; c++) {
        int co = cob * 16 + cg * 4 + c;
        float bv = (co < CO) ? bias[co] : 0.f;
        acc[0][0][c] = bv; acc[0][1][c] = bv; acc[1][0][c] = bv; acc[1][1][c] = bv;
    }

    for (int ci = 0; ci < CI; ci++) {
        __syncthreads();
        const float* xp = x + ((size_t)(n * CI + ci)) * (HI * WI);
        if (tid < 81) {
            int r = tid / 9, cc = tid - r * 9;
            int ig = i0 + r, jg = j0 + cc;
            float v = 0.f;
            if (ig < HI && jg < WI) v = xp[ig * WI + jg];
            xs[tid] = v;
        }
        if (tid < 144) {
            int k = tid >> 4, cl = tid & 15;
            int co = cob * 16 + cl;
            // flipped kernel: w2[co][ci][k] = w[ci][co][8-k]
            wsm[k][cl] = (co < CO) ? w[((size_t)ci * CO + co) * 9 + (8 - k)] : 0.f;
        }
        __syncthreads();
        #pragma unroll
        for (int kh = 0; kh < 3; kh++) {
            const int dy = (kh + 1) & 1;
            const int il = sy + (kh >> 1);
            #pragma unroll
            for (int kw = 0; kw < 3; kw++) {
                const int dx = (kw + 1) & 1;
                const int jl = sx + (kw >> 1);
                float4 wv = *(const float4*)&wsm[kh * 3 + kw][cg * 4];
                float xv = xs[il * 9 + jl];
                acc[dy][dx][0] += xv * wv.x;
                acc[dy][dx][1] += xv * wv.y;
                acc[dy][dx][2] += xv * wv.z;
                acc[dy][dx][3] += xv * wv.w;
            }
        }
    }
    #pragma unroll
    for (int dy = 0; dy < 2; dy++)
    #pragma unroll
    for (int dx = 0; dx < 2; dx++)
    #pragma unroll
    for (int c = 0; c < 4; c++) {
        int co = cob * 16 + cg * 4 + c;
        if (co < CO)
            y[(((size_t)n * CO + co) * HO + OH0 + 2 * sy + dy) * WO + OW0 + 2 * sx + dx] = acc[dy][dx][c];
    }
}

// ================= batchnorm stats =================
__global__ __launch_bounds__(256) void bn_stats1(const float* __restrict__ y, float2* __restrict__ part,
                                                 int C, int HW, int S)
{
    const int tid = threadIdx.x;
    const int c = blockIdx.x;
    const int by = blockIdx.y;          // n*S + s
    const int n = by / S, s = by - n * S;
    const int len = HW / S;
    const float* p = y + ((size_t)n * C + c) * HW + (size_t)s * len;
    float sum = 0.f, sq = 0.f;
    for (int i = tid; i < len; i += 256) { float v = p[i]; sum += v; sq += v * v; }
    __shared__ float ssum[256], ssq[256];
    ssum[tid] = sum; ssq[tid] = sq;
    __syncthreads();
    for (int o = 128; o > 0; o >>= 1) {
        if (tid < o) { ssum[tid] += ssum[tid + o]; ssq[tid] += ssq[tid + o]; }
        __syncthreads();
    }
    if (tid == 0) part[(size_t)c * gridDim.y + by] = make_float2(ssum[0], ssq[0]);
}

__global__ void bn_stats2(const float2* __restrict__ part, const float* __restrict__ g,
                          const float* __restrict__ be, float* __restrict__ sc, float* __restrict__ sh,
                          int C, int P, float invM)
{
    for (int c = threadIdx.x; c < C; c += 256) {
        float s = 0.f, q = 0.f;
        for (int i = 0; i < P; i++) { float2 v = part[(size_t)c * P + i]; s += v.x; q += v.y; }
        float m = s * invM;
        float var = q * invM - m * m;
        float scale = g[c] * rsqrtf(var + BN_EPS);
        sc[c] = scale; sh[c] = be[c] - m * scale;
    }
}

__global__ __launch_bounds__(256) void bn_apply_gelu(float* __restrict__ y, const float* __restrict__ sc,
                                                     const float* __restrict__ sh, int C, int HW, int n4)
{
    int i = blockIdx.x * 256 + threadIdx.x;
    if (i >= n4) return;
    float4 v = ((float4*)y)[i];
    int c = ((i * 4) / HW) % C;
    float s = sc[c], h = sh[c];
    v.x = gelu_exact(v.x * s + h);
    v.y = gelu_exact(v.y * s + h);
    v.z = gelu_exact(v.z * s + h);
    v.w = gelu_exact(v.w * s + h);
    ((float4*)y)[i] = v;
}

__global__ __launch_bounds__(256) void bn_apply_gelu_tanh(const float* __restrict__ y, float* __restrict__ out,
                                                          const float* __restrict__ sc, const float* __restrict__ sh,
                                                          int C, int HW, int n4, const float* __restrict__ lossacc)
{
    int i = blockIdx.x * 256 + threadIdx.x;
    if (i < n4) {
        float4 v = ((const float4*)y)[i];
        int c = ((i * 4) / HW) % C;
        float s = sc[c], h = sh[c];
        v.x = tanhf(gelu_exact(v.x * s + h));
        v.y = tanhf(gelu_exact(v.y * s + h));
        v.z = tanhf(gelu_exact(v.z * s + h));
        v.w = tanhf(gelu_exact(v.w * s + h));
        ((float4*)out)[i] = v;
    }
    if (blockIdx.x == 0 && threadIdx.x == 0)
        out[3145728] = lossacc[0] * (1.25f / 2097152.0f);
}

// ================= VQ =================
__global__ __launch_bounds__(256) void transpose_emb(const float* __restrict__ emb, float* __restrict__ embT)
{
    __shared__ float t[32][33];
    const int e0 = blockIdx.x * 32, c0 = blockIdx.y * 32;
    const int tx = threadIdx.x & 31, ty = threadIdx.x >> 5;
    #pragma unroll
    for (int j = 0; j < 4; j++) {
        int r = ty + j * 8;
        t[r][tx] = emb[(size_t)(e0 + r) * 512 + c0 + tx];
    }
    __syncthreads();
    #pragma unroll
    for (int j = 0; j < 4; j++) {
        int r = ty + j * 8;
        embT[(size_t)(c0 + r) * 2048 + e0 + tx] = t[tx][r];
    }
}

__global__ __launch_bounds__(256) void emb_norms(const float* __restrict__ emb, float* __restrict__ ee)
{
    const int wv = threadIdx.x >> 6, lane = threadIdx.x & 63;
    const int e = blockIdx.x * 4 + wv;
    float s = 0.f;
    #pragma unroll
    for (int j = 0; j < 8; j++) { float v = emb[(size_t)e * 512 + lane + j * 64]; s += v * v; }
    for (int o = 32; o > 0; o >>= 1) s += __shfl_down(s, o);
    if (lane == 0) ee[e] = s;
}

__global__ void zero_loss(float* p) { p[0] = 0.f; }

// scores s(v,e) = ee[e] - 2*dot(f_v, emb_e); per-(vtile,etile) block computes 64x64 and
// reduces to per-v (min,argmin) over its 64-e slice.
__global__ __launch_bounds__(256) void vq_scores_min(const float* __restrict__ h, const float* __restrict__ embT,
                                                     const float* __restrict__ ee,
                                                     float* __restrict__ minval, int* __restrict__ minidx)
{
    __shared__ __align__(16) float F[16][64];
    __shared__ __align__(16) float E[16][64];
    __shared__ float rv[64][16];
    __shared__ int   ri[64][16];
    const int tid = threadIdx.x;
    const int ty = tid >> 4, tx = tid & 15;
    const int v0 = blockIdx.x * 64, e0 = blockIdx.y * 64;
    const int n = v0 >> 8, p0 = v0 & 255;
    float acc[4][4] = {};

    for (int k0 = 0; k0 < 512; k0 += 16) {
        __syncthreads();
        for (int i = tid; i < 1024; i += 256) {
            int k = i >> 6, l = i & 63;
            F[k][l] = h[((size_t)(n * 512) + k0 + k) * 256 + p0 + l];
            E[k][l] = embT[(size_t)(k0 + k) * 2048 + e0 + l];
        }
        __syncthreads();
        #pragma unroll
        for (int k = 0; k < 16; k++) {
            float4 a = *(const float4*)&F[k][ty * 4];
            float4 b = *(const float4*)&E[k][tx * 4];
            acc[0][0] += a.x * b.x; acc[0][1] += a.x * b.y; acc[0][2] += a.x * b.z; acc[0][3] += a.x * b.w;
            acc[1][0] += a.y * b.x; acc[1][1] += a.y * b.y; acc[1][2] += a.y * b.z; acc[1][3] += a.y * b.w;
            acc[2][0] += a.z * b.x; acc[2][1] += a.z * b.y; acc[2][2] += a.z * b.z; acc[2][3] += a.z * b.w;
            acc[3][0] += a.w * b.x; acc[3][1] += a.w * b.y; acc[3][2] += a.w * b.z; acc[3][3] += a.w * b.w;
        }
    }
    #pragma unroll
    for (int i = 0; i < 4; i++) {
        float best = 1e30f; int bi = 0;
        #pragma unroll
        for (int j = 0; j < 4; j++) {
            int e = e0 + tx * 4 + j;
            float s = ee[e] - 2.f * acc[i][j];
            if (s < best) { best = s; bi = e; }
        }
        rv[ty * 4 + i][tx] = best; ri[ty * 4 + i][tx] = bi;
    }
    __syncthreads();
    if (tid < 64) {
        float best = rv[tid][0]; int bi = ri[tid][0];
        for (int t = 1; t < 16; t++) {
            float v = rv[tid][t]; int ix = ri[tid][t];
            if (v < best || (v == best && ix < bi)) { best = v; bi = ix; }
        }
        minval[(size_t)(v0 + tid) * 32 + blockIdx.y] = best;
        minidx[(size_t)(v0 + tid) * 32 + blockIdx.y] = bi;
    }
}

// reduce 32 candidates per vector, recompute d2 directly, accumulate loss sum
__global__ __launch_bounds__(256) void vq_finalize(const float* __restrict__ h, const float* __restrict__ emb,
                                                   const float* __restrict__ minval, const int* __restrict__ minidx,
                                                   float* __restrict__ lossacc)
{
    const int tid = threadIdx.x;
    const int g = tid >> 5, l = tid & 31;
    const int v = blockIdx.x * 8 + g;
    float val = minval[(size_t)v * 32 + l];
    int   idx = minidx[(size_t)v * 32 + l];
    for (int o = 16; o > 0; o >>= 1) {
        float v2 = __shfl_down(val, o, 32);
        int   i2 = __shfl_down(idx, o, 32);
        if (v2 < val || (v2 == val && i2 < idx)) { val = v2; idx = i2; }
    }
    idx = __shfl(idx, 0, 32);
    const int n = v >> 8, p = v & 255;
    float s = 0.f;
    #pragma unroll
    for (int j = 0; j < 16; j++) {
        int c = l + 32 * j;
        float f = h[((size_t)(n * 512) + c) * 256 + p];
        float e = emb[(size_t)idx * 512 + c];
        float d = f - e;
        s += d * d;
    }
    for (int o = 16; o > 0; o >>= 1) s += __shfl_down(s, o, 32);
    if (l == 0) atomicAdd(lossacc, s);
}

// ================= host =================
extern "C" void kernel_launch(void* const* d_in, const int* in_sizes, int n_in,
                              void* d_out, int out_size, void* d_ws, size_t ws_size,
                              hipStream_t stream)
{
    const float* x = (const float*)d_in[0];
    const float *ew[4], *ebi[4], *eg[4], *ebe[4];
    const float *dw[4], *dbi[4], *dg[4], *dbe[4];
    for (int i = 0; i < 4; i++) {
        ew[i]  = (const float*)d_in[1 + 4 * i];
        ebi[i] = (const float*)d_in[2 + 4 * i];
        eg[i]  = (const float*)d_in[3 + 4 * i];
        ebe[i] = (const float*)d_in[4 + 4 * i];
        dw[i]  = (const float*)d_in[17 + 4 * i];
        dbi[i] = (const float*)d_in[18 + 4 * i];
        dg[i]  = (const float*)d_in[19 + 4 * i];
        dbe[i] = (const float*)d_in[20 + 4 * i];
    }
    const float* emb = (const float*)d_in[33];
    float* out = (float*)d_out;
    float* ws = (float*)d_ws;

    float* bufA   = ws;                       // 16,777,216
    float* bufB   = ws + 16777216;            // 16,777,216
    float* embT   = ws + 33554432;            // 1,048,576
    float* ee     = ws + 34603008;            // 2,048
    float* part   = ws + 34605056;            // 32,768 (float2 area)
    float* sc     = ws + 34637824;            // 512
    float* sh     = ws + 34638336;            // 512
    float* minval = ws + 34638848;            // 131,072
    int*   minidx = (int*)(ws + 34638848 + 131072);
    float* lossacc = ws + 34638848 + 262144;

    auto bn = [&](float* y, const float* g, const float* be, int C, int HW, int S) {
        bn_stats1<<<dim3(C, 16 * S), 256, 0, stream>>>(y, (float2*)part, C, HW, S);
        bn_stats2<<<1, 256, 0, stream>>>((const float2*)part, g, be, sc, sh, C, 16 * S, 1.f / (16.f * HW));
    };

    // ---- encoder ----
    enc_conv<3, 64, 256, 256><<<dim3(64, 4, 16), 256, 0, stream>>>(x, ew[0], ebi[0], bufA);
    bn(bufA, eg[0], ebe[0], 64, 16384, 4);
    bn_apply_gelu<<<16384, 256, 0, stream>>>(bufA, sc, sh, 64, 16384, 4194304);

    enc_conv<64, 128, 128, 128><<<dim3(16, 8, 16), 256, 0, stream>>>(bufA, ew[1], ebi[1], bufB);
    bn(bufB, eg[1], ebe[1], 128, 4096, 2);
    bn_apply_gelu<<<8192, 256, 0, stream>>>(bufB, sc, sh, 128, 4096, 2097152);

    enc_conv<128, 256, 64, 64><<<dim3(4, 16, 16), 256, 0, stream>>>(bufB, ew[2], ebi[2], bufA);
    bn(bufA, eg[2], ebe[2], 256, 1024, 1);
    bn_apply_gelu<<<4096, 256, 0, stream>>>(bufA, sc, sh, 256, 1024, 1048576);

    enc_conv<256, 512, 32, 32><<<dim3(1, 32, 16), 256, 0, stream>>>(bufA, ew[3], ebi[3], bufB);
    bn(bufB, eg[3], ebe[3], 512, 256, 1);
    bn_apply_gelu<<<2048, 256, 0, stream>>>(bufB, sc, sh, 512, 256, 524288);
    // h = bufB (16,512,16,16)

    // ---- VQ ----
    transpose_emb<<<dim3(64, 16), 256, 0, stream>>>(emb, embT);
    emb_norms<<<512, 256, 0, stream>>>(emb, ee);
    zero_loss<<<1, 1, 0, stream>>>(lossacc);
    vq_scores_min<<<dim3(64, 32), 256, 0, stream>>>(bufB, embT, ee, minval, minidx);
    vq_finalize<<<512, 256, 0, stream>>>(bufB, emb, minval, minidx, lossacc);

    // ---- decoder (input = h, faithful to source) ----
    dec_conv<512, 256, 16, 16><<<dim3(4, 16, 16), 256, 0, stream>>>(bufB, dw[0], dbi[0], bufA);
    bn(bufA, dg[0], dbe[0], 256, 1024, 1);
    bn_apply_gelu<<<4096, 256, 0, stream>>>(bufA, sc, sh, 256, 1024, 1048576);

    dec_conv<256, 128, 32, 32><<<dim3(16, 8, 16), 256, 0, stream>>>(bufA, dw[1], dbi[1], bufB);
    bn(bufB, dg[1], dbe[1], 128, 4096, 2);
    bn_apply_gelu<<<8192, 256, 0, stream>>>(bufB, sc, sh, 128, 4096, 2097152);

    dec_conv<128, 64, 64, 64><<<dim3(64, 4, 16), 256, 0, stream>>>(bufB, dw[2], dbi[2], bufA);
    bn(bufA, dg[2], dbe[2], 64, 16384, 4);
    bn_apply_gelu<<<16384, 256, 0, stream>>>(bufA, sc, sh, 64, 16384, 4194304);

    dec_conv<64, 3, 128, 128><<<dim3(256, 1, 16), 256, 0, stream>>>(bufA, dw[3], dbi[3], bufB);
    bn(bufB, dg[3], dbe[3], 3, 65536, 32);
    bn_apply_gelu_tanh<<<3072, 256, 0, stream>>>(bufB, out, sc, sh, 3, 65536, 786432, lossacc);
}

// Round 2
// 1550.684 us; speedup vs baseline: 1.8206x; 1.8206x over previous
//
#include <hip/hip_runtime.h>
#include <math.h>

typedef _Float16 half8 __attribute__((ext_vector_type(8)));
typedef _Float16 half4t __attribute__((ext_vector_type(4)));
typedef float floatx4 __attribute__((ext_vector_type(4)));

// ============================================================================
// ConvDesc: geometry for implicit-GEMM conv (enc: stride-2 conv; dec: convT
// decomposed into 4 output-parity classes, each a uniform GEMM).
// A row (pixel p of class output grid) gathers, per tap, CI contiguous fp16.
// K ordering = tap-major then ci, matching wB blocked layout.
// ============================================================================
struct ConvDesc {
  int HI, WI;        // input spatial
  int CIs;           // log2 of input channel stride (CI)
  int OYs, OXs;      // log2 of class output grid
  int SXY;           // input coord multiplier (2 enc, 1 dec)
  int osxy;          // output coord multiplier (1 enc, 2 dec)
  int HO, WO;        // full output spatial
  int CO_pad, CO_real, CO_store;
  int nclass;
  int py[4], px[4], nt[4];
  int tt[4][9], tdy[4][9], tdx[4][9];
};

// ============================================================================
// conv_gemm<BM,BN>: 256 threads = 4 waves in 2x2; wave tile (BM/2)x(BN/2) of
// 16x16x32 f16 MFMAs. LDS A: [4][BM][8] (k-blocked), B: [BN/64][4][64][8].
// ============================================================================
template<int BM, int BN>
__global__ __launch_bounds__(256) void conv_gemm(
    const _Float16* __restrict__ act, const _Float16* __restrict__ wB,
    const float* __restrict__ bias, _Float16* __restrict__ y, ConvDesc d)
{
  constexpr int WM = BM / 2, WN = BN / 2, FM = WM / 16, FN = WN / 16;
  constexpr int ARPT = BM / 64, BT = BN / 64;
  __shared__ _Float16 As[4 * BM * 8];
  __shared__ _Float16 Bs[BT * 2048];

  const int tid = threadIdx.x;
  const int cls = blockIdx.z;
  const int m0 = blockIdx.x * BM, n0 = blockIdx.y * BN;
  const int CI = 1 << d.CIs;
  const int q = tid & 3, r0 = tid >> 2;

  int aih[ARPT], aiw[ARPT], abase[ARPT];
  #pragma unroll
  for (int i = 0; i < ARPT; i++) {
    int p = m0 + r0 + i * 64;
    int n  = p >> (d.OYs + d.OXs);
    int oy = (p >> d.OXs) & ((1 << d.OYs) - 1);
    int ox = p & ((1 << d.OXs) - 1);
    aih[i] = oy * d.SXY;
    aiw[i] = ox * d.SXY;
    abase[i] = n * d.HI;
  }

  floatx4 acc[FM][FN] = {};
  const int wv = tid >> 6, lane = tid & 63;
  const int wm = wv >> 1, wn = wv & 1;
  const int fr = lane >> 4, fc = lane & 15;
  const int nt = d.nt[cls];

  for (int ti = 0; ti < nt; ti++) {
    const int dy = d.tdy[cls][ti], dx = d.tdx[cls][ti];
    const int kt0 = d.tt[cls][ti] << (d.CIs - 5);
    for (int c5 = 0; c5 < (CI >> 5); c5++) {
      const int c0 = c5 << 5;
      // stage A: thread loads 16B (8 ci) of pixel r0(+64)
      #pragma unroll
      for (int i = 0; i < ARPT; i++) {
        int ih = aih[i] + dy, iw = aiw[i] + dx;
        half8 v = {};
        if ((unsigned)ih < (unsigned)d.HI && (unsigned)iw < (unsigned)d.WI)
          v = *(const half8*)(act + ((((size_t)(abase[i] + ih)) * d.WI + iw) << d.CIs) + c0 + q * 8);
        *(half8*)(As + q * (BM * 8) + (r0 + i * 64) * 8) = v;
      }
      // stage B: straight copy of pre-blocked 4KB tile(s)
      #pragma unroll
      for (int j = 0; j < BT; j++) {
        const _Float16* src = wB + (size_t)((kt0 + c5) * (d.CO_pad >> 6) + (n0 >> 6) + j) * 2048 + tid * 8;
        *(half8*)(Bs + j * 2048 + tid * 8) = *(const half8*)src;
      }
      __syncthreads();
      half8 af[FM], bf[FN];
      #pragma unroll
      for (int a = 0; a < FM; a++)
        af[a] = *(const half8*)(As + fr * (BM * 8) + (wm * WM + a * 16 + fc) * 8);
      #pragma unroll
      for (int b = 0; b < FN; b++) {
        int col = wn * WN + b * 16 + fc;
        bf[b] = *(const half8*)(Bs + (col >> 6) * 2048 + fr * 512 + (col & 63) * 8);
      }
      #pragma unroll
      for (int a = 0; a < FM; a++)
        #pragma unroll
        for (int b = 0; b < FN; b++)
          acc[a][b] = __builtin_amdgcn_mfma_f32_16x16x32_f16(af[a], bf[b], acc[a][b], 0, 0, 0);
      __syncthreads();
    }
  }

  // epilogue: D[row=(lane>>4)*4+rr][col=lane&15]
  float bv[FN];
  int colg[FN];
  #pragma unroll
  for (int b = 0; b < FN; b++) {
    int col = n0 + wn * WN + b * 16 + fc;
    colg[b] = col;
    bv[b] = (col < d.CO_real) ? bias[col] : 0.f;
  }
  const int pyc = d.py[cls], pxc = d.px[cls];
  #pragma unroll
  for (int a = 0; a < FM; a++) {
    #pragma unroll
    for (int rr = 0; rr < 4; rr++) {
      int m = m0 + wm * WM + a * 16 + fr * 4 + rr;
      int n  = m >> (d.OYs + d.OXs);
      int oy = (m >> d.OXs) & ((1 << d.OYs) - 1);
      int ox = m & ((1 << d.OXs) - 1);
      size_t opix = ((size_t)(n * d.HO + oy * d.osxy + pyc)) * d.WO + ox * d.osxy + pxc;
      _Float16* dst = y + opix * d.CO_store;
      #pragma unroll
      for (int b = 0; b < FN; b++)
        if (colg[b] < d.CO_store)
          dst[colg[b]] = (_Float16)(acc[a][b][rr] + bv[b]);
    }
  }
}

// ============================================================================
// VQ GEMM: scores = ee[e] - 2*f.e over (4096 f) x (2048 e), K=512; fused
// per-128-e argmin epilogue. Same tile structure as conv_gemm<128,128>.
// ============================================================================
__global__ __launch_bounds__(256) void vq_gemm(const _Float16* __restrict__ h,
    const _Float16* __restrict__ embB, const float* __restrict__ ee,
    float* __restrict__ minval, int* __restrict__ minidx)
{
  __shared__ char smem[32768];
  _Float16* As = (_Float16*)smem;            // [4][128][8]
  _Float16* Bs = (_Float16*)(smem + 8192);   // [2][2048]
  const int tid = threadIdx.x;
  const int m0 = blockIdx.x * 128, n0 = blockIdx.y * 128;
  const int q = tid & 3, r0 = tid >> 2;
  floatx4 acc[4][4] = {};
  const int wv = tid >> 6, lane = tid & 63;
  const int wm = wv >> 1, wn = wv & 1;
  const int fr = lane >> 4, fc = lane & 15;

  for (int c5 = 0; c5 < 16; c5++) {
    #pragma unroll
    for (int i = 0; i < 2; i++) {
      half8 v = *(const half8*)(h + (size_t)(m0 + r0 + i * 64) * 512 + c5 * 32 + q * 8);
      *(half8*)(As + q * 1024 + (r0 + i * 64) * 8) = v;
    }
    #pragma unroll
    for (int j = 0; j < 2; j++)
      *(half8*)(Bs + j * 2048 + tid * 8) =
          *(const half8*)(embB + (size_t)(c5 * 32 + (n0 >> 6) + j) * 2048 + tid * 8);
    __syncthreads();
    half8 af[4], bf[4];
    #pragma unroll
    for (int a = 0; a < 4; a++)
      af[a] = *(const half8*)(As + fr * 1024 + (wm * 64 + a * 16 + fc) * 8);
    #pragma unroll
    for (int b = 0; b < 4; b++) {
      int col = wn * 64 + b * 16 + fc;
      bf[b] = *(const half8*)(Bs + (col >> 6) * 2048 + fr * 512 + (col & 63) * 8);
    }
    #pragma unroll
    for (int a = 0; a < 4; a++)
      #pragma unroll
      for (int b = 0; b < 4; b++)
        acc[a][b] = __builtin_amdgcn_mfma_f32_16x16x32_f16(af[a], bf[b], acc[a][b], 0, 0, 0);
    __syncthreads();
  }

  float* sval = (float*)smem;            // [128][32]
  int*   sidx = (int*)(smem + 16384);    // [128][32]
  #pragma unroll
  for (int a = 0; a < 4; a++) {
    #pragma unroll
    for (int rr = 0; rr < 4; rr++) {
      int rb = wm * 64 + a * 16 + fr * 4 + rr;
      float best = 1e30f; int bi = 0;
      #pragma unroll
      for (int b = 0; b < 4; b++) {
        int e = n0 + wn * 64 + b * 16 + fc;
        float s = ee[e] - 2.f * acc[a][b][rr];
        if (s < best) { best = s; bi = e; }
      }
      sval[rb * 32 + wn * 16 + fc] = best;
      sidx[rb * 32 + wn * 16 + fc] = bi;
    }
  }
  __syncthreads();
  if (tid < 128) {
    float best = sval[tid * 32]; int bi = sidx[tid * 32];
    for (int t = 1; t < 32; t++) {
      float v = sval[tid * 32 + t]; int ix = sidx[tid * 32 + t];
      if (v < best || (v == best && ix < bi)) { best = v; bi = ix; }
    }
    minval[(size_t)(m0 + tid) * 16 + blockIdx.y] = best;
    minidx[(size_t)(m0 + tid) * 16 + blockIdx.y] = bi;
  }
}

__global__ __launch_bounds__(256) void vq_finalize(const _Float16* __restrict__ h,
    const float* __restrict__ emb, const float* __restrict__ minval,
    const int* __restrict__ minidx, float* __restrict__ lossacc)
{
  const int tid = threadIdx.x;
  const int g = tid >> 4, l = tid & 15;
  const int v = blockIdx.x * 16 + g;
  float val = minval[(size_t)v * 16 + l];
  int   idx = minidx[(size_t)v * 16 + l];
  #pragma unroll
  for (int o = 8; o > 0; o >>= 1) {
    float v2 = __shfl_down(val, o, 16);
    int   i2 = __shfl_down(idx, o, 16);
    if (v2 < val || (v2 == val && i2 < idx)) { val = v2; idx = i2; }
  }
  idx = __shfl(idx, 0, 16);
  float s = 0.f;
  #pragma unroll
  for (int j = 0; j < 32; j++) {
    int c = l + 16 * j;
    float f = (float)h[(size_t)v * 512 + c];
    float e = emb[(size_t)idx * 512 + c];
    float dd = f - e;
    s += dd * dd;
  }
  #pragma unroll
  for (int o = 8; o > 0; o >>= 1) s += __shfl_down(s, o, 16);
  if (l == 0) atomicAdd(lossacc, s);
}

// ============================================================================
// BN (training-mode) over NHWC fp16
// ============================================================================
__global__ __launch_bounds__(256) void bn_stats1(const _Float16* __restrict__ y,
    float2* __restrict__ part, int Cs, int RB)
{
  const int C = 1 << Cs;
  const int tid = threadIdx.x;
  const size_t rbase = (size_t)blockIdx.x * RB;
  if (C == 512) {
    float s = 0.f, qq = 0.f, s2 = 0.f, q2 = 0.f;
    for (int i = 0; i < RB; i++) {
      const _Float16* row = y + (rbase + i) * 512;
      float v1 = (float)row[tid], v2 = (float)row[tid + 256];
      s += v1; qq += v1 * v1; s2 += v2; q2 += v2 * v2;
    }
    part[(size_t)blockIdx.x * 512 + tid] = make_float2(s, qq);
    part[(size_t)blockIdx.x * 512 + tid + 256] = make_float2(s2, q2);
  } else {
    const int c = tid & (C - 1), g = tid >> Cs, G = 256 >> Cs;
    float s = 0.f, qq = 0.f;
    for (int rr = g; rr < RB; rr += G) {
      float v = (float)y[((rbase + rr) << Cs) + c];
      s += v; qq += v * v;
    }
    __shared__ float rs[256], rq[256];
    rs[tid] = s; rq[tid] = qq;
    __syncthreads();
    for (int off = 128; off >= C; off >>= 1) {
      if (tid < off) { rs[tid] += rs[tid + off]; rq[tid] += rq[tid + off]; }
      __syncthreads();
    }
    if (tid < C) part[(size_t)blockIdx.x * C + tid] = make_float2(rs[tid], rq[tid]);
  }
}

__global__ void bn_stats2(const float2* __restrict__ part, const float* __restrict__ g,
                          const float* __restrict__ be, float* __restrict__ sc,
                          float* __restrict__ sh, int C, int C_real, int NB, float invM)
{
  for (int c = threadIdx.x; c < C; c += 256) {
    float s = 0.f, qv = 0.f;
    for (int i = 0; i < NB; i++) { float2 v = part[(size_t)i * C + c]; s += v.x; qv += v.y; }
    float m = s * invM, var = qv * invM - m * m;
    float gg = (c < C_real) ? g[c] : 1.f;
    float bb = (c < C_real) ? be[c] : 0.f;
    float scale = gg * rsqrtf(var + 1e-5f);
    sc[c] = scale; sh[c] = bb - m * scale;
  }
}

__global__ __launch_bounds__(256) void bn_apply(_Float16* __restrict__ y,
    const float* __restrict__ sc, const float* __restrict__ sh, int Cs, int n8)
{
  int i = blockIdx.x * 256 + threadIdx.x;
  if (i >= n8) return;
  int c0 = (i << 3) & ((1 << Cs) - 1);
  half8 v = *(half8*)(y + (size_t)i * 8);
  half8 o;
  #pragma unroll
  for (int j = 0; j < 8; j++) {
    float x = (float)v[j] * sc[c0 + j] + sh[c0 + j];
    o[j] = (_Float16)(0.5f * x * (1.f + erff(x * 0.70710678118654752f)));
  }
  *(half8*)(y + (size_t)i * 8) = o;
}

__global__ __launch_bounds__(256) void bn_final(const _Float16* __restrict__ y,
    float* __restrict__ out, const float* __restrict__ sc, const float* __restrict__ sh,
    const float* __restrict__ lossacc)
{
  int p = blockIdx.x * 256 + threadIdx.x;  // 1,048,576 pixels
  int n = p >> 16, hw = p & 65535;
  half4t v = *(const half4t*)(y + (size_t)p * 4);
  #pragma unroll
  for (int c = 0; c < 3; c++) {
    float x = (float)v[c] * sc[c] + sh[c];
    float gg = 0.5f * x * (1.f + erff(x * 0.70710678118654752f));
    out[(size_t)(n * 3 + c) * 65536 + hw] = tanhf(gg);
  }
  if (p == 0) out[3145728] = lossacc[0] * (1.25f / 2097152.0f);
}

// ============================================================================
// layout transforms
// ============================================================================
__global__ __launch_bounds__(256) void x_to_nhwc(const float* __restrict__ x,
                                                 _Float16* __restrict__ xp)
{
  int p = blockIdx.x * 256 + threadIdx.x;
  int n = p >> 16, hw = p & 65535;
  half8 v0 = {};
  v0[0] = (_Float16)x[(size_t)(n * 3 + 0) * 65536 + hw];
  v0[1] = (_Float16)x[(size_t)(n * 3 + 1) * 65536 + hw];
  v0[2] = (_Float16)x[(size_t)(n * 3 + 2) * 65536 + hw];
  half8 z = {};
  _Float16* d = xp + (size_t)p * 32;
  *(half8*)d = v0; *(half8*)(d + 8) = z; *(half8*)(d + 16) = z; *(half8*)(d + 24) = z;
}

// wB[(kt*(CO_pad/64)+jt)*2048 + kg*512 + cc*8 + kj]; k = tap*CI + ci
__global__ __launch_bounds__(256) void wtrans(const float* __restrict__ w,
    _Float16* __restrict__ wB, int CIs, int CI_real, int COs, int CO_real, int is_dec)
{
  int idx = blockIdx.x * 256 + threadIdx.x;
  int CO_pad = 1 << COs;
  int K = 9 << CIs;
  if (idx >= K * CO_pad) return;
  int k = idx >> COs, co = idx & (CO_pad - 1);
  int tap = k >> CIs, ci = k & ((1 << CIs) - 1);
  int kh = tap / 3, kw = tap - kh * 3;
  float v = 0.f;
  if (ci < CI_real && co < CO_real)
    v = is_dec ? w[(((size_t)ci * CO_real + co) * 3 + kh) * 3 + kw]
               : w[(((size_t)co * CI_real + ci) * 3 + kh) * 3 + kw];
  int kt = k >> 5, kg = (k >> 3) & 3, kj = k & 7, jt = co >> 6, cc = co & 63;
  wB[(size_t)(kt * (CO_pad >> 6) + jt) * 2048 + kg * 512 + cc * 8 + kj] = (_Float16)v;
}

__global__ __launch_bounds__(256) void embtrans(const float* __restrict__ emb,
                                                _Float16* __restrict__ embB)
{
  int idx = blockIdx.x * 256 + threadIdx.x;  // 512*2048
  int k = idx >> 11, e = idx & 2047;
  float v = emb[(size_t)e * 512 + k];
  int kt = k >> 5, kg = (k >> 3) & 3, kj = k & 7, jt = e >> 6, cc = e & 63;
  embB[(size_t)(kt * 32 + jt) * 2048 + kg * 512 + cc * 8 + kj] = (_Float16)v;
}

__global__ __launch_bounds__(256) void emb_norms(const float* __restrict__ emb,
                                                 float* __restrict__ ee)
{
  const int wv = threadIdx.x >> 6, lane = threadIdx.x & 63;
  const int e = blockIdx.x * 4 + wv;
  float s = 0.f;
  #pragma unroll
  for (int j = 0; j < 8; j++) { float v = emb[(size_t)e * 512 + lane + j * 64]; s += v * v; }
  for (int o = 32; o > 0; o >>= 1) s += __shfl_down(s, o);
  if (lane == 0) ee[e] = s;
}

__global__ void zero_loss(float* p) { p[0] = 0.f; }

// ============================================================================
// host
// ============================================================================
static ConvDesc enc_desc(int HI, int WI, int CIs, int CO) {
  ConvDesc d = {};
  d.HI = HI; d.WI = WI; d.CIs = CIs;
  int HO = HI / 2, WO = WI / 2;
  d.OYs = __builtin_ctz(HO); d.OXs = __builtin_ctz(WO);
  d.SXY = 2; d.osxy = 1; d.HO = HO; d.WO = WO;
  d.CO_pad = CO; d.CO_real = CO; d.CO_store = CO;
  d.nclass = 1; d.py[0] = 0; d.px[0] = 0; d.nt[0] = 9;
  for (int t = 0; t < 9; t++) { d.tt[0][t] = t; d.tdy[0][t] = t / 3 - 1; d.tdx[0][t] = t % 3 - 1; }
  return d;
}

static ConvDesc dec_desc(int HI, int WI, int CIs, int CO_pad, int CO_real, int CO_store) {
  ConvDesc d = {};
  d.HI = HI; d.WI = WI; d.CIs = CIs;
  d.OYs = __builtin_ctz(HI); d.OXs = __builtin_ctz(WI);
  d.SXY = 1; d.osxy = 2; d.HO = 2 * HI; d.WO = 2 * WI;
  d.CO_pad = CO_pad; d.CO_real = CO_real; d.CO_store = CO_store;
  d.nclass = 4;
  // parity 0: {(k=1,di=0)}; parity 1: {(k=0,di=1),(k=2,di=0)}  (y[o]=sum x[i]w[k], o=2i+k-1)
  int kys[2][2] = {{1, -1}, {0, 2}}, dis[2][2] = {{0, -1}, {1, 0}}, cnt[2] = {1, 2};
  for (int py = 0; py < 2; py++)
    for (int px = 0; px < 2; px++) {
      int c = py * 2 + px; d.py[c] = py; d.px[c] = px;
      int m = 0;
      for (int a = 0; a < cnt[py]; a++)
        for (int b = 0; b < cnt[px]; b++) {
          d.tt[c][m] = kys[py][a] * 3 + kys[px][b];
          d.tdy[c][m] = dis[py][a]; d.tdx[c][m] = dis[px][b]; m++;
        }
      d.nt[c] = m;
    }
  return d;
}

extern "C" void kernel_launch(void* const* d_in, const int* in_sizes, int n_in,
                              void* d_out, int out_size, void* d_ws, size_t ws_size,
                              hipStream_t stream)
{
  const float* x = (const float*)d_in[0];
  const float *ew[4], *ebi[4], *eg[4], *ebe[4];
  const float *dw[4], *dbi[4], *dg[4], *dbe[4];
  for (int i = 0; i < 4; i++) {
    ew[i]  = (const float*)d_in[1 + 4 * i];
    ebi[i] = (const float*)d_in[2 + 4 * i];
    eg[i]  = (const float*)d_in[3 + 4 * i];
    ebe[i] = (const float*)d_in[4 + 4 * i];
    dw[i]  = (const float*)d_in[17 + 4 * i];
    dbi[i] = (const float*)d_in[18 + 4 * i];
    dg[i]  = (const float*)d_in[19 + 4 * i];
    dbe[i] = (const float*)d_in[20 + 4 * i];
  }
  const float* emb = (const float*)d_in[33];
  float* out = (float*)d_out;
  _Float16* wsh = (_Float16*)d_ws;

  // memory map (halfs)
  _Float16* bufA = wsh;                       // 33,554,432 halfs (xp aliases here)
  _Float16* xp   = wsh;
  _Float16* bufB = wsh + 33554432;            // 16,777,216
  size_t wboff = 50331648;
  _Float16* wbE[4], *wbD[4];
  size_t wbsz[8] = {18432, 73728, 294912, 1179648, 1179648, 294912, 73728, 36864};
  for (int i = 0; i < 4; i++) { wbE[i] = wsh + wboff; wboff += wbsz[i]; }
  for (int i = 0; i < 4; i++) { wbD[i] = wsh + wboff; wboff += wbsz[4 + i]; }
  _Float16* embB = wsh + wboff;               // 1,048,576 -> ends 54,532,096
  float* f32 = (float*)(wsh + 54532096);
  float2* part  = (float2*)f32;               // 65536 float2
  float* sc     = f32 + 131072;
  float* sh     = f32 + 131584;
  float* ee     = f32 + 132096;
  float* minval = f32 + 134144;               // 65536
  int*   minidx = (int*)(f32 + 199680);       // 65536
  float* lossacc= f32 + 265216;

  // ---- transforms ----
  x_to_nhwc<<<4096, 256, 0, stream>>>(x, xp);
  wtrans<<<72, 256, 0, stream>>>(ew[0], wbE[0], 5, 3, 6, 64, 0);
  wtrans<<<288, 256, 0, stream>>>(ew[1], wbE[1], 6, 64, 7, 128, 0);
  wtrans<<<1152, 256, 0, stream>>>(ew[2], wbE[2], 7, 128, 8, 256, 0);
  wtrans<<<4608, 256, 0, stream>>>(ew[3], wbE[3], 8, 256, 9, 512, 0);
  wtrans<<<4608, 256, 0, stream>>>(dw[0], wbD[0], 9, 512, 8, 256, 1);
  wtrans<<<1152, 256, 0, stream>>>(dw[1], wbD[1], 8, 256, 7, 128, 1);
  wtrans<<<288, 256, 0, stream>>>(dw[2], wbD[2], 7, 128, 6, 64, 1);
  wtrans<<<144, 256, 0, stream>>>(dw[3], wbD[3], 6, 64, 6, 3, 1);
  embtrans<<<4096, 256, 0, stream>>>(emb, embB);
  emb_norms<<<512, 256, 0, stream>>>(emb, ee);
  zero_loss<<<1, 1, 0, stream>>>(lossacc);

  auto bn = [&](_Float16* y, const float* g, const float* be, int Cs, int C_real,
                int P) {
    int C = 1 << Cs;
    int RB = P / 128;
    bn_stats1<<<128, 256, 0, stream>>>(y, part, Cs, RB);
    bn_stats2<<<1, 256, 0, stream>>>(part, g, be, sc, sh, C, C_real, 128, 1.f / (float)P);
  };

  // ---- encoder ----
  {
    ConvDesc d = enc_desc(256, 256, 5, 64);
    conv_gemm<128, 64><<<dim3(2048, 1, 1), 256, 0, stream>>>(xp, wbE[0], ebi[0], bufB, d);
    bn(bufB, eg[0], ebe[0], 6, 64, 262144);
    bn_apply<<<8192, 256, 0, stream>>>(bufB, sc, sh, 6, 2097152);
  }
  {
    ConvDesc d = enc_desc(128, 128, 6, 128);
    conv_gemm<128, 128><<<dim3(512, 1, 1), 256, 0, stream>>>(bufB, wbE[1], ebi[1], bufA, d);
    bn(bufA, eg[1], ebe[1], 7, 128, 65536);
    bn_apply<<<4096, 256, 0, stream>>>(bufA, sc, sh, 7, 1048576);
  }
  {
    ConvDesc d = enc_desc(64, 64, 7, 256);
    conv_gemm<128, 128><<<dim3(128, 2, 1), 256, 0, stream>>>(bufA, wbE[2], ebi[2], bufB, d);
    bn(bufB, eg[2], ebe[2], 8, 256, 16384);
    bn_apply<<<2048, 256, 0, stream>>>(bufB, sc, sh, 8, 524288);
  }
  {
    ConvDesc d = enc_desc(32, 32, 8, 512);
    conv_gemm<64, 64><<<dim3(64, 8, 1), 256, 0, stream>>>(bufB, wbE[3], ebi[3], bufA, d);
    bn(bufA, eg[3], ebe[3], 9, 512, 4096);
    bn_apply<<<1024, 256, 0, stream>>>(bufA, sc, sh, 9, 262144);
  }
  _Float16* h = bufA;  // (16,16,16,512) NHWC

  // ---- VQ ----
  vq_gemm<<<dim3(32, 16), 256, 0, stream>>>(h, embB, ee, minval, minidx);
  vq_finalize<<<256, 256, 0, stream>>>(h, emb, minval, minidx, lossacc);

  // ---- decoder ----
  {
    ConvDesc d = dec_desc(16, 16, 9, 256, 256, 256);
    conv_gemm<64, 64><<<dim3(64, 4, 4), 256, 0, stream>>>(h, wbD[0], dbi[0], bufB, d);
    bn(bufB, dg[0], dbe[0], 8, 256, 16384);
    bn_apply<<<2048, 256, 0, stream>>>(bufB, sc, sh, 8, 524288);
  }
  {
    ConvDesc d = dec_desc(32, 32, 8, 128, 128, 128);
    conv_gemm<128, 128><<<dim3(128, 1, 4), 256, 0, stream>>>(bufB, wbD[1], dbi[1], bufA, d);
    bn(bufA, dg[1], dbe[1], 7, 128, 65536);
    bn_apply<<<4096, 256, 0, stream>>>(bufA, sc, sh, 7, 1048576);
  }
  {
    ConvDesc d = dec_desc(64, 64, 7, 64, 64, 64);
    conv_gemm<128, 64><<<dim3(512, 1, 4), 256, 0, stream>>>(bufA, wbD[2], dbi[2], bufB, d);
    bn(bufB, dg[2], dbe[2], 6, 64, 262144);
    bn_apply<<<8192, 256, 0, stream>>>(bufB, sc, sh, 6, 2097152);
  }
  {
    ConvDesc d = dec_desc(128, 128, 6, 64, 3, 4);
    conv_gemm<128, 64><<<dim3(2048, 1, 4), 256, 0, stream>>>(bufB, wbD[3], dbi[3], bufA, d);
    bn(bufA, dg[3], dbe[3], 2, 3, 1048576);
    bn_final<<<4096, 256, 0, stream>>>(bufA, out, sc, sh, lossacc);
  }
}